// Round 1
// baseline (135.758 us; speedup 1.0000x reference)
//
#include <hip/hip_runtime.h>
#include <hip/hip_bf16.h>

#define NN 1024
#define LN_EPS 1e-5f

typedef __bf16 bf16x8 __attribute__((ext_vector_type(8)));
typedef float floatx4 __attribute__((ext_vector_type(4)));

// Kernel 1: A'[i][h] = sum_d emb[i][d]*W1[d][h] + b1[h]   (row-major [1024][64])
//           Bt[h][j] = sum_d emb[j][d]*W1[64+d][h]        (transposed [64][1024])
__global__ void precompute_ab(const float* __restrict__ emb, const float* __restrict__ W1,
                              const float* __restrict__ b1, float* __restrict__ Ap,
                              float* __restrict__ Bt) {
    __shared__ __align__(16) float e[64];
    int i = blockIdx.x, h = threadIdx.x;
    e[h] = emb[i * 64 + h];
    __syncthreads();
    float a = b1[h], b = 0.f;
#pragma unroll
    for (int d = 0; d < 64; d++) {
        a = fmaf(e[d], W1[d * 64 + h], a);
        b = fmaf(e[d], W1[(64 + d) * 64 + h], b);
    }
    Ap[i * 64 + h] = a;
    Bt[h * NN + i] = b;
}

// Kernel 2: pack W2^T into MFMA A-fragment order (bf16).
// A-frag for mfma_f32_16x16x32_bf16: lane l holds A[m][k], m = l&15, k = (l>>4)*8 + t.
// Here A = W2^T, i.e. A[m=h'][k] = W2[k][h'].
// Layout: Wf[((mt*2+kc)*64 + lane)*8 + t] so the main kernel loads one coalesced b128/lane.
__global__ void prep_w2(const float* __restrict__ W2, __bf16* __restrict__ Wf) {
    int lane = threadIdx.x;
    int m_l = lane & 15, kg = lane >> 4;
#pragma unroll
    for (int mt = 0; mt < 4; mt++)
#pragma unroll
        for (int kc = 0; kc < 2; kc++) {
            bf16x8 f;
#pragma unroll
            for (int t = 0; t < 8; t++) {
                int k = kc * 32 + kg * 8 + t;
                f[t] = (__bf16)W2[k * 64 + mt * 16 + m_l];
            }
            *(bf16x8*)&Wf[((mt * 2 + kc) * 64 + lane) * 8] = f;
        }
}

// Kernel 3: fused pair-MLP. Block = 256 thr = 4 waves. Block b: i = b>>2,
// wave w covers j in [ (b&3)*256 + w*64 , +64 ).  Lane = pair within the wave tile.
__global__ __launch_bounds__(256) void fused(
    const float* __restrict__ Ap, const float* __restrict__ Bt, const __bf16* __restrict__ Wf,
    const float* __restrict__ g1, const float* __restrict__ be1, const float* __restrict__ b2,
    const float* __restrict__ g2, const float* __restrict__ be2, const float* __restrict__ W3,
    const float* __restrict__ b3, const float* __restrict__ mask, float* __restrict__ out) {
    __shared__ __align__(16) float Arow[64], G1[64], BE1[64], B2s[64], G2s[64], BE2s[64], W3s[64];
    __shared__ __align__(16) __bf16 h1t[4][64 * 64];  // per-wave 8KB bf16 h1 tile, XOR-swizzled

    int tid = threadIdx.x;
    int wave = tid >> 6, lane = tid & 63;
    int i = blockIdx.x >> 2;
    int j0 = (blockIdx.x & 3) * 256 + wave * 64;

    if (tid < 64) {
        Arow[tid] = Ap[i * 64 + tid];
        G1[tid] = g1[tid];  BE1[tid] = be1[tid];
        B2s[tid] = b2[tid]; G2s[tid] = g2[tid]; BE2s[tid] = be2[tid];
        W3s[tid] = W3[tid];
    }
    __syncthreads();

    int m_l = lane & 15, kg = lane >> 4;

    // W2^T fragments, coalesced loads from prepacked buffer
    bf16x8 afrag[4][2];
#pragma unroll
    for (int mt = 0; mt < 4; mt++)
#pragma unroll
        for (int kc = 0; kc < 2; kc++)
            afrag[mt][kc] = *(const bf16x8*)&Wf[((mt * 2 + kc) * 64 + lane) * 8];

    // ---- Stage 1: pre1 = A'[i] + Bt[:, j]   (lane = pair, transposed in regs) ----
    float x[64];
    float s = 0.f, sq = 0.f;
    const float* btp = Bt + j0 + lane;
#pragma unroll
    for (int h4 = 0; h4 < 16; h4++) {
        floatx4 ar = *(const floatx4*)&Arow[h4 * 4];
#pragma unroll
        for (int u = 0; u < 4; u++) {
            float v = ar[u] + btp[(h4 * 4 + u) * NN];
            x[h4 * 4 + u] = v;
            s += v;
            sq = fmaf(v, v, sq);
        }
    }
    float m1 = s * 0.015625f;
    float var1 = fmaf(m1, -m1, sq * 0.015625f);
    float rs1 = rsqrtf(var1 + LN_EPS);

    // ---- LN1 + ReLU -> bf16, write own row to LDS (chunk XOR-swizzle: conflict-free) ----
    __bf16* rowp = &h1t[wave][lane * 64];
    int sw = lane & 7;
#pragma unroll
    for (int c = 0; c < 8; c++) {
        floatx4 ga = *(const floatx4*)&G1[c * 8], gb = *(const floatx4*)&G1[c * 8 + 4];
        floatx4 ea = *(const floatx4*)&BE1[c * 8], eb = *(const floatx4*)&BE1[c * 8 + 4];
        bf16x8 fr;
#pragma unroll
        for (int t = 0; t < 8; t++) {
            float g = (t < 4) ? ga[t] : gb[t - 4];
            float e = (t < 4) ? ea[t] : eb[t - 4];
            float hv = fmaf((x[c * 8 + t] - m1) * rs1, g, e);
            fr[t] = (__bf16)fmaxf(hv, 0.f);
        }
        *(bf16x8*)(rowp + ((c ^ sw) * 8)) = fr;
    }
    // wave-private tile: DS ops per-wave are in-order; just drain before cross-lane reads
    asm volatile("s_waitcnt lgkmcnt(0)" ::: "memory");

    // ---- MFMA: pre2^T = W2^T @ h1^T ; C rows = h', cols = pairs ----
    floatx4 acc[4][4];
#pragma unroll
    for (int a = 0; a < 4; a++)
#pragma unroll
        for (int b = 0; b < 4; b++) acc[a][b] = (floatx4){0.f, 0.f, 0.f, 0.f};

    const __bf16* wbase = &h1t[wave][0];
#pragma unroll
    for (int nt = 0; nt < 4; nt++) {
        int pair = nt * 16 + m_l;
#pragma unroll
        for (int kc = 0; kc < 2; kc++) {
            int chunk = kc * 4 + kg;
            bf16x8 bfrag = *(const bf16x8*)(wbase + pair * 64 + ((chunk ^ (pair & 7)) * 8));
#pragma unroll
            for (int mt = 0; mt < 4; mt++)
                acc[mt][nt] =
                    __builtin_amdgcn_mfma_f32_16x16x32_bf16(afrag[mt][kc], bfrag, acc[mt][nt], 0, 0, 0);
        }
    }

    float b3v = b3[0];

    // ---- Epilogue: +b2, LN2, ReLU, dot W3, mask. Lane holds h' = mt*16+kg*4+r, pair col = nt*16+m_l
#pragma unroll
    for (int nt = 0; nt < 4; nt++) {
        float s2 = 0.f, q2 = 0.f;
#pragma unroll
        for (int mt = 0; mt < 4; mt++) {
            floatx4 bb = *(const floatx4*)&B2s[mt * 16 + kg * 4];
#pragma unroll
            for (int r = 0; r < 4; r++) {
                float v = acc[mt][nt][r] + bb[r];
                s2 += v;
                q2 = fmaf(v, v, q2);
            }
        }
        s2 += __shfl_xor(s2, 16); s2 += __shfl_xor(s2, 32);
        q2 += __shfl_xor(q2, 16); q2 += __shfl_xor(q2, 32);
        float m2 = s2 * 0.015625f;
        float var2 = fmaf(m2, -m2, q2 * 0.015625f);
        float rs2 = rsqrtf(var2 + LN_EPS);

        float sc = 0.f;
#pragma unroll
        for (int mt = 0; mt < 4; mt++) {
            floatx4 bb = *(const floatx4*)&B2s[mt * 16 + kg * 4];
            floatx4 gg = *(const floatx4*)&G2s[mt * 16 + kg * 4];
            floatx4 ee = *(const floatx4*)&BE2s[mt * 16 + kg * 4];
            floatx4 ww = *(const floatx4*)&W3s[mt * 16 + kg * 4];
#pragma unroll
            for (int r = 0; r < 4; r++) {
                float v = acc[mt][nt][r] + bb[r];
                float h2 = fmaxf(fmaf((v - m2) * rs2, gg[r], ee[r]), 0.f);
                sc = fmaf(h2, ww[r], sc);
            }
        }
        sc += __shfl_xor(sc, 16); sc += __shfl_xor(sc, 32);

        if (kg == 0) {
            int j = j0 + nt * 16 + m_l;
            int p = i * NN + j;
            out[p] = (i == j) ? 0.f : (sc + b3v) * mask[p];
        }
    }
}

extern "C" void kernel_launch(void* const* d_in, const int* in_sizes, int n_in,
                              void* d_out, int out_size, void* d_ws, size_t ws_size,
                              hipStream_t stream) {
    const float* emb = (const float*)d_in[0];
    const float* mask = (const float*)d_in[1];
    const float* W1 = (const float*)d_in[2];
    const float* b1 = (const float*)d_in[3];
    const float* g1 = (const float*)d_in[4];
    const float* be1 = (const float*)d_in[5];
    const float* W2 = (const float*)d_in[6];
    const float* b2 = (const float*)d_in[7];
    const float* g2 = (const float*)d_in[8];
    const float* be2 = (const float*)d_in[9];
    const float* W3 = (const float*)d_in[10];
    const float* b3 = (const float*)d_in[11];
    float* out = (float*)d_out;

    float* Ap = (float*)d_ws;            // 1024*64 f32 = 256 KB
    float* Bt = Ap + 1024 * 64;          // 64*1024 f32 = 256 KB
    __bf16* Wf = (__bf16*)(Bt + 64 * 1024);  // 4096 bf16 = 8 KB

    precompute_ab<<<1024, 64, 0, stream>>>(emb, W1, b1, Ap, Bt);
    prep_w2<<<1, 64, 0, stream>>>(W2, Wf);
    fused<<<4096, 256, 0, stream>>>(Ap, Bt, Wf, g1, be1, b2, g2, be2, W3, b3, mask, out);
}

// Round 2
// 113.810 us; speedup vs baseline: 1.1929x; 1.1929x over previous
//
#include <hip/hip_runtime.h>
#include <hip/hip_bf16.h>

#define NN 1024
#define LN_EPS 1e-5f

typedef __bf16 bf16x8 __attribute__((ext_vector_type(8)));
typedef float floatx4 __attribute__((ext_vector_type(4)));
typedef float floatx2 __attribute__((ext_vector_type(2)));

// Kernel 1 (blocks 0..1023): per-node precompute.
//   Ap[i][h] = emb[i]·W1[:64,h] + b1[h]         (row-major [1024][64])
//   Bt[h][j] = emb[j]·W1[64:,h]                 (transposed [64][1024])
//   sumA[i] = Σ_h Ap[i][h], sumB[j] = Σ_h Bt[h][j]   (mean of pre1 is linear!)
// Block 1024: pack W2^T into MFMA A-fragment order (bf16), one b128/lane load later.
__global__ void precompute_ab(const float* __restrict__ emb, const float* __restrict__ W1,
                              const float* __restrict__ b1, const float* __restrict__ W2,
                              float* __restrict__ Ap, float* __restrict__ Bt,
                              float* __restrict__ sumA, float* __restrict__ sumB,
                              __bf16* __restrict__ Wf) {
    if (blockIdx.x == 1024) {
        // A-frag for mfma_f32_16x16x32_bf16: lane l holds A[m][k], m=l&15, k=(l>>4)*8+t.
        // A = W2^T: A[m=h'][k] = W2[k][h'].
        int lane = threadIdx.x;
        int m_l = lane & 15, kg = lane >> 4;
#pragma unroll
        for (int mt = 0; mt < 4; mt++)
#pragma unroll
            for (int kc = 0; kc < 2; kc++) {
                bf16x8 f;
#pragma unroll
                for (int t = 0; t < 8; t++) {
                    int k = kc * 32 + kg * 8 + t;
                    f[t] = (__bf16)W2[k * 64 + mt * 16 + m_l];
                }
                *(bf16x8*)&Wf[((mt * 2 + kc) * 64 + lane) * 8] = f;
            }
        return;
    }
    __shared__ __align__(16) float e[64];
    int i = blockIdx.x, h = threadIdx.x;
    e[h] = emb[i * 64 + h];
    __syncthreads();
    float a = b1[h], b = 0.f;
#pragma unroll
    for (int d = 0; d < 64; d++) {
        a = fmaf(e[d], W1[d * 64 + h], a);
        b = fmaf(e[d], W1[(64 + d) * 64 + h], b);
    }
    Ap[i * 64 + h] = a;
    Bt[h * NN + i] = b;
    float ra = a, rb = b;
#pragma unroll
    for (int off = 1; off < 64; off <<= 1) {
        ra += __shfl_xor(ra, off);
        rb += __shfl_xor(rb, off);
    }
    if (h == 0) { sumA[i] = ra; sumB[i] = rb; }
}

// Kernel 2: fused pair-MLP. Block = 256 thr = 4 waves. Block b: i = b>>2,
// wave w covers j in [ (b&3)*256 + w*64 , +64 ).  Lane = pair within the wave tile.
// All pointwise math written on float2 ext-vectors -> v_pk_*_f32 (VOP3P dual-FP32).
__global__ __launch_bounds__(256, 4) void fused(
    const float* __restrict__ Ap, const float* __restrict__ Bt, const __bf16* __restrict__ Wf,
    const float* __restrict__ sumA, const float* __restrict__ sumB,
    const float* __restrict__ g1, const float* __restrict__ be1, const float* __restrict__ b2,
    const float* __restrict__ g2, const float* __restrict__ be2, const float* __restrict__ W3,
    const float* __restrict__ b3, const float* __restrict__ mask, float* __restrict__ out) {
    __shared__ __align__(16) float Arow[64], G1[64], BE1[64], B2s[64], G2s[64], BE2s[64], W3s[64];
    __shared__ __align__(16) __bf16 h1t[4][64 * 64];  // per-wave 8KB bf16 h1 tile, XOR-swizzled

    int tid = threadIdx.x;
    int wave = tid >> 6, lane = tid & 63;
    int i = blockIdx.x >> 2;
    int j0 = (blockIdx.x & 3) * 256 + wave * 64;

    if (tid < 64) {
        Arow[tid] = Ap[i * 64 + tid];
        G1[tid] = g1[tid];  BE1[tid] = be1[tid];
        B2s[tid] = b2[tid]; G2s[tid] = g2[tid]; BE2s[tid] = be2[tid];
        W3s[tid] = W3[tid];
    }
    __syncthreads();

    int m_l = lane & 15, kg = lane >> 4;

    // W2^T fragments, coalesced loads from prepacked buffer
    bf16x8 afrag[4][2];
#pragma unroll
    for (int mt = 0; mt < 4; mt++)
#pragma unroll
        for (int kc = 0; kc < 2; kc++)
            afrag[mt][kc] = *(const bf16x8*)&Wf[((mt * 2 + kc) * 64 + lane) * 8];

    // ---- Stage 1: x = A'[i] + Bt[:, j]  (lane = pair, transposed in regs) ----
    float sBj = sumB[j0 + lane];
    const float* btp = Bt + j0 + lane;
    floatx2 x2[32];
    floatx2 qa = {0.f, 0.f}, qb = {0.f, 0.f};
#pragma unroll
    for (int h2 = 0; h2 < 32; h2++) {
        floatx2 bb = { btp[(2 * h2) * NN], btp[(2 * h2 + 1) * NN] };
        floatx2 aa = *(const floatx2*)&Arow[2 * h2];
        floatx2 v = aa + bb;           // v_pk_add_f32
        x2[h2] = v;
        if (h2 & 1) qb += v * v;       // v_pk_fma_f32
        else        qa += v * v;
    }
    floatx2 qs = qa + qb;
    float sq = qs[0] + qs[1];
    float m1 = (sumA[i] + sBj) * 0.015625f;   // mean is linear in A,B
    float var1 = fmaf(m1, -m1, sq * 0.015625f);
    float rs1 = rsqrtf(var1 + LN_EPS);
    floatx2 p1 = {rs1, rs1};
    float ofs = -m1 * rs1;
    floatx2 o1 = {ofs, ofs};

    // ---- LN1 + ReLU -> bf16, write own row to LDS (chunk XOR-swizzle: conflict-free) ----
    __bf16* rowp = &h1t[wave][lane * 64];
    int sw = lane & 7;
#pragma unroll
    for (int c = 0; c < 8; c++) {
        bf16x8 fr;
#pragma unroll
        for (int t = 0; t < 4; t++) {
            floatx2 gg = *(const floatx2*)&G1[c * 8 + 2 * t];
            floatx2 ee = *(const floatx2*)&BE1[c * 8 + 2 * t];
            floatx2 xn = x2[c * 4 + t] * p1 + o1;   // v_pk_fma_f32
            floatx2 y  = xn * gg + ee;              // v_pk_fma_f32
            y = __builtin_elementwise_max(y, (floatx2){0.f, 0.f});  // v_pk_max_f32
            fr[2 * t]     = (__bf16)y[0];
            fr[2 * t + 1] = (__bf16)y[1];
        }
        *(bf16x8*)(rowp + ((c ^ sw) * 8)) = fr;
    }
    // wave-private tile: DS ops per-wave are in-order; just drain before cross-lane reads
    asm volatile("s_waitcnt lgkmcnt(0)" ::: "memory");

    // ---- MFMA: pre2^T = W2^T @ h1^T ; C rows = h', cols = pairs ----
    floatx4 acc[4][4];
#pragma unroll
    for (int a = 0; a < 4; a++)
#pragma unroll
        for (int b = 0; b < 4; b++) acc[a][b] = (floatx4){0.f, 0.f, 0.f, 0.f};

    const __bf16* wbase = &h1t[wave][0];
#pragma unroll
    for (int nt = 0; nt < 4; nt++) {
        int pair = nt * 16 + m_l;
#pragma unroll
        for (int kc = 0; kc < 2; kc++) {
            int chunk = kc * 4 + kg;
            bf16x8 bfrag = *(const bf16x8*)(wbase + pair * 64 + ((chunk ^ (pair & 7)) * 8));
#pragma unroll
            for (int mt = 0; mt < 4; mt++)
                acc[mt][nt] =
                    __builtin_amdgcn_mfma_f32_16x16x32_bf16(afrag[mt][kc], bfrag, acc[mt][nt], 0, 0, 0);
        }
    }

    float b3v = b3[0];

    // ---- Epilogue: +b2, LN2, ReLU, dot W3, mask. Lane holds h' = mt*16+kg*4+r, pair = nt*16+m_l
#pragma unroll
    for (int nt = 0; nt < 4; nt++) {
        floatx2 s2v = {0.f, 0.f}, q2v = {0.f, 0.f};
#pragma unroll
        for (int mt = 0; mt < 4; mt++) {
            floatx2 blo = *(const floatx2*)&B2s[mt * 16 + kg * 4];
            floatx2 bhi = *(const floatx2*)&B2s[mt * 16 + kg * 4 + 2];
            floatx2 vlo = { acc[mt][nt][0], acc[mt][nt][1] };
            floatx2 vhi = { acc[mt][nt][2], acc[mt][nt][3] };
            vlo += blo; vhi += bhi;                  // v_pk_add_f32
            acc[mt][nt][0] = vlo[0]; acc[mt][nt][1] = vlo[1];
            acc[mt][nt][2] = vhi[0]; acc[mt][nt][3] = vhi[1];
            s2v += vlo; s2v += vhi;                  // v_pk_add_f32
            q2v += vlo * vlo; q2v += vhi * vhi;      // v_pk_fma_f32
        }
        float s2 = s2v[0] + s2v[1];
        float q2 = q2v[0] + q2v[1];
        s2 += __shfl_xor(s2, 16); s2 += __shfl_xor(s2, 32);
        q2 += __shfl_xor(q2, 16); q2 += __shfl_xor(q2, 32);
        float m2 = s2 * 0.015625f;
        float var2 = fmaf(m2, -m2, q2 * 0.015625f);
        float rs2 = rsqrtf(var2 + LN_EPS);
        floatx2 p2 = {rs2, rs2};
        float o2s = -m2 * rs2;
        floatx2 o2 = {o2s, o2s};

        floatx2 scv = {0.f, 0.f};
#pragma unroll
        for (int mt = 0; mt < 4; mt++) {
#pragma unroll
            for (int hh = 0; hh < 2; hh++) {
                floatx2 g = *(const floatx2*)&G2s[mt * 16 + kg * 4 + 2 * hh];
                floatx2 e = *(const floatx2*)&BE2s[mt * 16 + kg * 4 + 2 * hh];
                floatx2 w = *(const floatx2*)&W3s[mt * 16 + kg * 4 + 2 * hh];
                floatx2 v = { acc[mt][nt][2 * hh], acc[mt][nt][2 * hh + 1] };
                floatx2 xn = v * p2 + o2;            // v_pk_fma_f32
                floatx2 y  = xn * g + e;             // v_pk_fma_f32
                y = __builtin_elementwise_max(y, (floatx2){0.f, 0.f});
                scv += y * w;                        // v_pk_fma_f32
            }
        }
        float sc = scv[0] + scv[1];
        sc += __shfl_xor(sc, 16); sc += __shfl_xor(sc, 32);

        if (kg == 0) {
            int j = j0 + nt * 16 + m_l;
            int p = i * NN + j;
            out[p] = (i == j) ? 0.f : (sc + b3v) * mask[p];
        }
    }
}

extern "C" void kernel_launch(void* const* d_in, const int* in_sizes, int n_in,
                              void* d_out, int out_size, void* d_ws, size_t ws_size,
                              hipStream_t stream) {
    const float* emb = (const float*)d_in[0];
    const float* mask = (const float*)d_in[1];
    const float* W1 = (const float*)d_in[2];
    const float* b1 = (const float*)d_in[3];
    const float* g1 = (const float*)d_in[4];
    const float* be1 = (const float*)d_in[5];
    const float* W2 = (const float*)d_in[6];
    const float* b2 = (const float*)d_in[7];
    const float* g2 = (const float*)d_in[8];
    const float* be2 = (const float*)d_in[9];
    const float* W3 = (const float*)d_in[10];
    const float* b3 = (const float*)d_in[11];
    float* out = (float*)d_out;

    float* Ap = (float*)d_ws;                 // 1024*64 f32 = 256 KB
    float* Bt = Ap + 1024 * 64;               // 64*1024 f32 = 256 KB
    float* sA = Bt + 64 * 1024;               // 1024 f32 = 4 KB
    float* sB = sA + 1024;                    // 1024 f32 = 4 KB
    __bf16* Wf = (__bf16*)(sB + 1024);        // 4096 bf16 = 8 KB

    precompute_ab<<<1025, 64, 0, stream>>>(emb, W1, b1, W2, Ap, Bt, sA, sB, Wf);
    fused<<<4096, 256, 0, stream>>>(Ap, Bt, Wf, sA, sB, g1, be1, b2, g2, be2, W3, b3, mask, out);
}